// Round 6
// baseline (3879.752 us; speedup 1.0000x reference)
//
#include <hip/hip_runtime.h>
#include <math.h>

// LPKT: one WG (1024 thr, 16 waves, 4 waves/SIMD) per batch element, 99-step
// recurrence in-kernel. h state (129x128 fp32) in registers, MFMA C-layout,
// 5 cb-blocks over quarter-WGs {2,1,1,1}; wave's MFMA d-block = 32*(w&3).
// GEMV phases k-split 4 ways (quarter = k-chunk), bf16 k-quad weights (uint2),
// features broadcast LDS->SGPR via v_readlane. W4h A-fragments are NOT persistent:
// prefetched into 32 transient VGPRs during phase C, consumed by MFMA after B7,
// dead by update -> peak live regs ~112 under the forced 128-VGPR cap (16 waves/CU).

#define BB   64
#define SS   100
#define NQ1  129
#define DK   128
#define NTH  1024

// ws dword map: [0,114688) bf16 weight quads, [114688,122880) W4h A-fragments
#define DW_W1A   0
#define DW_W1B   8192
#define DW_W2    16384
#define DW_W3    49152
#define DW_W4L   81920
#define DW_W4I   90112
#define DW_W5A   98304
#define DW_W5B   106496
#define DW_AFRAG 114688
#define DW_TOTAL 122880

typedef __attribute__((ext_vector_type(16))) float floatx16;
typedef __attribute__((ext_vector_type(8)))  short short8v;

__device__ __forceinline__ float frcp(float x) { return __builtin_amdgcn_rcpf(x); }
__device__ __forceinline__ float fsig(float x) { float t = __expf(-x); return frcp(1.0f + t); }
__device__ __forceinline__ float ftanh(float x) {
    x = fminf(20.0f, fmaxf(-20.0f, x));
    float t = __expf(-2.0f * x);
    return (1.0f - t) * frcp(1.0f + t);
}
__device__ __forceinline__ float rlf(float v, int s) {
    return __int_as_float(__builtin_amdgcn_readlane(__float_as_int(v), s));
}
__device__ __forceinline__ unsigned bfbits(float x) {   // fp32 -> bf16 RNE
    unsigned u = __float_as_uint(x);
    return (u + 0x7fffu + ((u >> 16) & 1u)) >> 16;
}
__device__ __forceinline__ float blo(unsigned u) { return __uint_as_float(u << 16); }
__device__ __forceinline__ float bhi(unsigned u) { return __uint_as_float(u & 0xffff0000u); }

// ---- prep: bf16 k-quad weight repack + W4h A-fragment pack (same as R5) ------
__global__ void prep_kernel(const float* __restrict__ W1, const float* __restrict__ W2,
                            const float* __restrict__ W3, const float* __restrict__ W4,
                            const float* __restrict__ W5, unsigned* __restrict__ ws) {
    int gidx = blockIdx.x * blockDim.x + threadIdx.x;
    if (gidx < DW_AFRAG) {
        const float* src; int koff, dw;
        if      (gidx < DW_W1B) { src = W1; koff = 0;   dw = gidx; }
        else if (gidx < DW_W2)  { src = W1; koff = 128; dw = gidx - DW_W1B; }
        else if (gidx < DW_W3)  { src = W2; koff = 0;   dw = gidx - DW_W2; }
        else if (gidx < DW_W4L) { src = W3; koff = 0;   dw = gidx - DW_W3; }
        else if (gidx < DW_W4I) { src = W4; koff = 128; dw = gidx - DW_W4L; }
        else if (gidx < DW_W5A) { src = W4; koff = 256; dw = gidx - DW_W4I; }
        else if (gidx < DW_W5B) { src = W5; koff = 0;   dw = gidx - DW_W5A; }
        else                    { src = W5; koff = 128; dw = gidx - DW_W5B; }
        int quad = dw >> 8, rem = dw & 255, d = rem >> 1, half = rem & 1;
        int k = koff + quad * 4 + half * 2;
        unsigned lo = bfbits(src[(size_t)k * 128 + d]);
        unsigned hi = bfbits(src[(size_t)(k + 1) * 128 + d]);
        ws[gidx] = lo | (hi << 16);
    } else if (gidx < DW_TOTAL) {
        int i = gidx - DW_AFRAG;
        int gg = i >> 11, kb = (i >> 8) & 7, lane = (i >> 2) & 63, c = i & 3;
        int m = lane & 31, hp = lane >> 5;
        int k0 = 16 * kb + 8 * hp + 2 * c;
        unsigned lo = bfbits(W4[(size_t)k0 * 128 + 32 * gg + m]);
        unsigned hi = bfbits(W4[(size_t)(k0 + 1) * 128 + 32 * gg + m]);
        ws[gidx] = lo | (hi << 16);
    }
}

// ---- main kernel --------------------------------------------------------------
__global__ __launch_bounds__(NTH)
void lpkt_kernel(const int* __restrict__ e_data, const int* __restrict__ a_data,
                 const int* __restrict__ it_data, const int* __restrict__ at_data,
                 const float* __restrict__ qm,  const float* __restrict__ h0,
                 const float* __restrict__ Ee,  const float* __restrict__ Eat,
                 const float* __restrict__ Eit,
                 const float* __restrict__ W1, const float* __restrict__ b1,
                 const float* __restrict__ W2, const float* __restrict__ b2,
                 const float* __restrict__ W3, const float* __restrict__ b3,
                 const float* __restrict__ W4, const float* __restrict__ b4,
                 const float* __restrict__ W5, const float* __restrict__ b5,
                 float* __restrict__ out, const unsigned* __restrict__ ws)
{
    const int b    = blockIdx.x;
    const int tid  = threadIdx.x;
    const int lane = tid & 63;
    const int w    = tid >> 6;       // 0..15
    const int g    = w & 3;          // MFMA d-block: rows 32g..32g+31
    const int qq   = w >> 2;         // quarter: GEMV k-chunk, cb owner
    const int h5   = lane >> 5;
    const int l31  = lane & 31;
    const int ncb  = (qq == 0) ? 2 : 1;   // qq0:{cb0,cb1}, qq1:{cb2}, qq2:{cb3}, qq3:{cb4}
    const int gd   = ((w & 1) << 6) | lane;   // GEMV output d
    const int gmat = (w >> 1) & 1;            // GEMV matrix select
    const uint2* wsu2 = (const uint2*)ws;

    __shared__ __align__(16) unsigned s_frag[10240];  // 40 KB B-fragments (kb*5+cb)
    __shared__ __align__(16) float s_feat[512];   // [lp | it | lc | h_tilde]
    __shared__ __align__(16) float s_eat[256];    // [e_row | at_row]
    __shared__ __align__(16) float s_enext[128];
    __shared__ float s_LG[128], s_c[128], s_s1[128];
    __shared__ __align__(16) float s_red[1024];   // [qq*256 + mat*128 + d]
    __shared__ float s_ht4[512];                  // [qq*128 + d]
    __shared__ float s_q[2][160];
    __shared__ float s_scal[2];

    float hreg[2][16];    // slot i: cb = (qq==0)? i : qq+1 ; n = 32*cb+l31,
                          // d = 32g+(r&3)+8*(r>>2)+4*h5

    // ---------------- prologue ----------------
    #pragma unroll
    for (int i = 0; i < 2; i++) {
        if (i < ncb) {
            const int cb = (qq == 0) ? i : (qq + 1);
            const int n = 32 * cb + l31;
            #pragma unroll
            for (int r = 0; r < 16; r++) {
                int d = 32 * g + (r & 3) + 8 * (r >> 2) + 4 * h5;
                hreg[i][r] = (n <= 128) ? h0[(size_t)n * DK + d] : 0.0f;
            }
            #pragma unroll
            for (int q = 0; q < 4; q++) {
                int kb = 2 * g + (q >> 1);
                int lanep = l31 + ((q & 1) << 5);
                int off = (((kb * 5 + cb) << 10) + lanep * 16 + (h5 << 3)) >> 2;
                unsigned lo = bfbits(hreg[i][4 * q])     | (bfbits(hreg[i][4 * q + 1]) << 16);
                unsigned hi = bfbits(hreg[i][4 * q + 2]) | (bfbits(hreg[i][4 * q + 3]) << 16);
                s_frag[off] = lo; s_frag[off + 1] = hi;
            }
        } else {
            #pragma unroll
            for (int r = 0; r < 16; r++) hreg[i][r] = 0.0f;
        }
    }
    {   // s1 partials: eighth = tid>>7, 16 k each (original fp32 W1)
        int et = tid >> 7, d = tid & 127;
        float z = 0.0f;
        for (int k = 16 * et; k < 16 * et + 16; k++) z += W1[(size_t)(256 + k) * DK + d];
        s_red[tid] = z;
    }
    if (tid < 160) {
        int e0 = e_data[b * SS];
        s_q[0][tid] = (tid < NQ1) ? qm[(size_t)e0 * NQ1 + tid] : 0.0f;
    }
    if (tid == 0) out[b * SS] = 0.0f;
    __syncthreads();
    if (tid < 128) {
        float s = 0.0f;
        #pragma unroll
        for (int j = 0; j < 8; j++) s += s_red[128 * j + tid];
        s_s1[tid] = s;
        s_feat[tid] = 0.0f;            // learning_pre = 0
    }
    if (w == 15) {
        float v = s_q[0][lane] + s_q[0][64 + lane] + ((lane < 32) ? s_q[0][128 + lane] : 0.0f);
        #pragma unroll
        for (int m = 32; m > 0; m >>= 1) v += __shfl_xor(v, m);
        if (lane == 0) s_scal[0] = v;
    }
    __syncthreads();
    {   // ht0 partials per quarter
        float ph[16];
        #pragma unroll
        for (int r = 0; r < 16; r++) ph[r] = 0.0f;
        #pragma unroll
        for (int i = 0; i < 2; i++) {
            const bool act = (i < ncb);
            const int cb = (qq == 0) ? i : (qq + 1);
            float qv = act ? s_q[0][32 * cb + l31] : 0.0f;
            #pragma unroll
            for (int r = 0; r < 16; r++) ph[r] += qv * hreg[i][r];
        }
        #pragma unroll
        for (int r = 0; r < 16; r++) {
            float v = ph[r];
            v += __shfl_xor(v, 1); v += __shfl_xor(v, 2); v += __shfl_xor(v, 4);
            v += __shfl_xor(v, 8); v += __shfl_xor(v, 16);
            if (l31 == 0) s_ht4[qq * 128 + 32 * g + (r & 3) + 8 * (r >> 2) + 4 * h5] = v;
        }
    }
    __syncthreads();
    if (tid < 128)
        s_feat[384 + tid] = (s_ht4[tid] + s_ht4[128 + tid] + s_ht4[256 + tid] + s_ht4[384 + tid])
                          * frcp(s_scal[0]);
    __syncthreads();

    // ---------------- recurrence ----------------
    for (int t = 0; t < SS - 1; t++) {
        const float* qcur = s_q[t & 1];
        float*       qnxt = s_q[(t + 1) & 1];
        const int base = b * SS + t;
        const int e_t  = e_data[base];
        const int at_t = at_data[base];
        const int it_t = it_data[base];
        const float afl = (float)a_data[base];
        const int e_nx = e_data[base + 1];

        // --- staging ---
        if (w < 4) {
            const float* src; float* dst;
            if      (w == 0) { src = Ee  + (size_t)e_t  * DK; dst = s_eat; }
            else if (w == 1) { src = Eat + (size_t)at_t * DK; dst = s_eat + 128; }
            else if (w == 2) { src = Eit + (size_t)it_t * DK; dst = s_feat + 128; }
            else             { src = Ee  + (size_t)e_nx * DK; dst = s_enext; }
            ((float2*)dst)[lane] = ((const float2*)src)[lane];
        } else if (tid >= 256 && tid < 416) {
            int idx = tid - 256;
            qnxt[idx] = (idx < NQ1) ? qm[(size_t)e_nx * NQ1 + idx] : 0.0f;
        }
        __syncthreads();   // B1

        // --- phase A: all_learning partials (wave15 also q_next sum) ---
        if (w == 15) {
            float v = qnxt[lane] + qnxt[64 + lane] + ((lane < 32) ? qnxt[128 + lane] : 0.0f);
            #pragma unroll
            for (int m = 32; m > 0; m >>= 1) v += __shfl_xor(v, m);
            if (lane == 0) s_scal[0] = v;
        }
        {
            const float4* rowp = (const float4*)(gmat ? (s_eat + 128) : s_eat);
            float4 fv = rowp[l31];
            const uint2* Wr = wsu2 + (gmat ? (DW_W1B / 2) : (DW_W1A / 2)) + gd;
            float z0 = 0.f, z1 = 0.f, z2 = 0.f, z3 = 0.f;
            #pragma unroll
            for (int s = 0; s < 8; s++) {
                uint2 wv = Wr[(8 * qq + s) * 128];
                int src = 8 * qq + s;
                z0 += rlf(fv.x, src) * blo(wv.x);  z1 += rlf(fv.y, src) * bhi(wv.x);
                z2 += rlf(fv.z, src) * blo(wv.y);  z3 += rlf(fv.w, src) * bhi(wv.y);
            }
            s_red[qq * 256 + gmat * 128 + gd] = (z0 + z1) + (z2 + z3);
        }
        __syncthreads();   // B2
        if (tid < 128) {
            float s = 0.0f;
            #pragma unroll
            for (int j = 0; j < 8; j++) s += s_red[128 * j + tid];
            s_feat[256 + tid] = b1[tid] + afl * s_s1[tid] + s;
        }
        __syncthreads();   // B3

        // --- phase B: feat(512) . W2 / W3, k quartered ---
        {
            float4 fv = ((const float4*)s_feat)[32 * qq + l31];
            const uint2* Wr = wsu2 + (gmat ? (DW_W3 / 2) : (DW_W2 / 2)) + gd;
            float z0 = 0.f, z1 = 0.f, z2 = 0.f, z3 = 0.f;
            #pragma unroll 16
            for (int s = 0; s < 32; s++) {
                uint2 wv = Wr[(32 * qq + s) * 128];
                z0 += rlf(fv.x, s) * blo(wv.x);  z1 += rlf(fv.y, s) * bhi(wv.x);
                z2 += rlf(fv.z, s) * blo(wv.y);  z3 += rlf(fv.w, s) * bhi(wv.y);
            }
            s_red[qq * 256 + gmat * 128 + gd] = (z0 + z1) + (z2 + z3);
        }
        __syncthreads();   // B4
        if (tid < 128) {
            float w2s = s_red[tid]       + s_red[256 + tid] + s_red[512 + tid] + s_red[768 + tid];
            float w3s = s_red[128 + tid] + s_red[384 + tid] + s_red[640 + tid] + s_red[896 + tid];
            s_LG[tid] = fsig(w3s + b3[tid]) * (ftanh(w2s + b2[tid]) + 1.0f) * 0.5f;
            s_feat[tid] = s_feat[256 + tid];   // lp <- lc
        }
        __syncthreads();   // B5

        // --- A-fragment prefetch (consumed at MFMA, 1+ phase of latency cover) ---
        uint4 afru[8];
        #pragma unroll
        for (int kb = 0; kb < 8; kb++)
            afru[kb] = ((const uint4*)ws)[(DW_AFRAG >> 2) + g * 512 + kb * 64 + lane];

        // --- phase C: LG.W4l + it.W4i ---
        {
            const float4* rowp = (const float4*)(gmat ? (s_feat + 128) : s_LG);
            float4 fv = rowp[l31];
            const uint2* Wr = wsu2 + (gmat ? (DW_W4I / 2) : (DW_W4L / 2)) + gd;
            float z0 = 0.f, z1 = 0.f, z2 = 0.f, z3 = 0.f;
            #pragma unroll
            for (int s = 0; s < 8; s++) {
                uint2 wv = Wr[(8 * qq + s) * 128];
                int src = 8 * qq + s;
                z0 += rlf(fv.x, src) * blo(wv.x);  z1 += rlf(fv.y, src) * bhi(wv.x);
                z2 += rlf(fv.z, src) * blo(wv.y);  z3 += rlf(fv.w, src) * bhi(wv.y);
            }
            s_red[qq * 256 + gmat * 128 + gd] = (z0 + z1) + (z2 + z3);
        }
        __syncthreads();   // B6
        if (tid < 128) {
            float s = 0.0f;
            #pragma unroll
            for (int j = 0; j < 8; j++) s += s_red[128 * j + tid];
            s_c[tid] = b4[tid] + s;
        }
        __syncthreads();   // B7

        // --- MFMA: logits for this quarter's cb set (reads OLD fragments) ---
        floatx16 acc[2];
        #pragma unroll
        for (int i = 0; i < 2; i++) acc[i] = (floatx16)(0.0f);
        #pragma unroll
        for (int i = 0; i < 2; i++) {
            if (i < ncb) {
                const int cb = (qq == 0) ? i : (qq + 1);
                floatx16 a = (floatx16)(0.0f);
                #pragma unroll
                for (int kb = 0; kb < 8; kb++) {
                    short8v bf = *(const short8v*)((const char*)s_frag + (((kb * 5 + cb) << 10) + lane * 16));
                    a = __builtin_amdgcn_mfma_f32_32x32x16_bf16(
                            __builtin_bit_cast(short8v, afru[kb]), bf, a, 0, 0, 0);
                }
                acc[i] = a;
            }
        }
        __syncthreads();   // B8: all fragment reads complete before rewrite

        // --- update: h = q*LG + sigmoid(logit+c)*h ; new fragments + h_tilde ---
        {
            float lgv[16], cv[16];
            #pragma unroll
            for (int r = 0; r < 16; r++) {
                int d = 32 * g + (r & 3) + 8 * (r >> 2) + 4 * h5;
                lgv[r] = s_LG[d];  cv[r] = s_c[d];
            }
            float ph[16];
            #pragma unroll
            for (int r = 0; r < 16; r++) ph[r] = 0.0f;
            #pragma unroll
            for (int i = 0; i < 2; i++) {
                const bool act = (i < ncb);
                const int cb = (qq == 0) ? i : (qq + 1);
                const int n = 32 * cb + l31;
                const float qcv = act ? qcur[n] : 0.0f;
                const float qnv = act ? qnxt[n] : 0.0f;
                const bool valid = act && ((cb < 4) || (l31 == 0));
                #pragma unroll
                for (int r = 0; r < 16; r++) {
                    float gg = fsig(acc[i][r] + cv[r]);
                    float hn = qcv * lgv[r] + gg * hreg[i][r];
                    hn = valid ? hn : 0.0f;
                    hreg[i][r] = hn;
                    ph[r] += qnv * hn;
                }
                if (act) {
                    #pragma unroll
                    for (int q = 0; q < 4; q++) {
                        int kb = 2 * g + (q >> 1);
                        int lanep = l31 + ((q & 1) << 5);
                        int off = (((kb * 5 + cb) << 10) + lanep * 16 + (h5 << 3)) >> 2;
                        unsigned lo = bfbits(hreg[i][4 * q])     | (bfbits(hreg[i][4 * q + 1]) << 16);
                        unsigned hi = bfbits(hreg[i][4 * q + 2]) | (bfbits(hreg[i][4 * q + 3]) << 16);
                        s_frag[off] = lo; s_frag[off + 1] = hi;
                    }
                }
            }
            #pragma unroll
            for (int r = 0; r < 16; r++) {
                float v = ph[r];
                v += __shfl_xor(v, 1); v += __shfl_xor(v, 2); v += __shfl_xor(v, 4);
                v += __shfl_xor(v, 8); v += __shfl_xor(v, 16);
                if (l31 == 0) s_ht4[qq * 128 + 32 * g + (r & 3) + 8 * (r >> 2) + 4 * h5] = v;
            }
        }
        __syncthreads();   // B9
        if (tid < 128)
            s_feat[384 + tid] = (s_ht4[tid] + s_ht4[128 + tid] + s_ht4[256 + tid] + s_ht4[384 + tid])
                              * frcp(s_scal[0]);
        __syncthreads();   // B10

        // --- phase E: [e_next, h_tilde] . W5 ---
        {
            const float4* rowp = (const float4*)(gmat ? (s_feat + 384) : s_enext);
            float4 fv = rowp[l31];
            const uint2* Wr = wsu2 + (gmat ? (DW_W5B / 2) : (DW_W5A / 2)) + gd;
            float z0 = 0.f, z1 = 0.f, z2 = 0.f, z3 = 0.f;
            #pragma unroll
            for (int s = 0; s < 8; s++) {
                uint2 wv = Wr[(8 * qq + s) * 128];
                int src = 8 * qq + s;
                z0 += rlf(fv.x, src) * blo(wv.x);  z1 += rlf(fv.y, src) * bhi(wv.x);
                z2 += rlf(fv.z, src) * blo(wv.y);  z3 += rlf(fv.w, src) * bhi(wv.y);
            }
            s_red[qq * 256 + gmat * 128 + gd] = (z0 + z1) + (z2 + z3);
        }
        __syncthreads();   // B11
        if (tid < 64) {
            float va = b5[lane], vb = b5[64 + lane];
            #pragma unroll
            for (int j = 0; j < 4; j++) {
                va += s_red[j * 256 + lane]      + s_red[j * 256 + 128 + lane];
                vb += s_red[j * 256 + 64 + lane] + s_red[j * 256 + 192 + lane];
            }
            float v = fsig(va) + fsig(vb);
            #pragma unroll
            for (int m = 32; m > 0; m >>= 1) v += __shfl_xor(v, m);
            if (lane == 0) out[base + 1] = v * (1.0f / 128.0f);
        }
        // no trailing barrier: next staging writes don't touch s_red; B1 orders the rest
    }
}

extern "C" void kernel_launch(void* const* d_in, const int* in_sizes, int n_in,
                              void* d_out, int out_size, void* d_ws, size_t ws_size,
                              hipStream_t stream) {
    const int*   e_data  = (const int*)d_in[0];
    const int*   a_data  = (const int*)d_in[1];
    const int*   it_data = (const int*)d_in[2];
    const int*   at_data = (const int*)d_in[3];
    const float* qm  = (const float*)d_in[4];
    const float* h0  = (const float*)d_in[5];
    const float* Ee  = (const float*)d_in[6];
    const float* Eat = (const float*)d_in[7];
    const float* Eit = (const float*)d_in[8];
    const float* W1  = (const float*)d_in[9];
    const float* b1  = (const float*)d_in[10];
    const float* W2  = (const float*)d_in[11];
    const float* b2  = (const float*)d_in[12];
    const float* W3  = (const float*)d_in[13];
    const float* b3  = (const float*)d_in[14];
    const float* W4  = (const float*)d_in[15];
    const float* b4  = (const float*)d_in[16];
    const float* W5  = (const float*)d_in[17];
    const float* b5  = (const float*)d_in[18];
    float* out = (float*)d_out;
    unsigned* ws = (unsigned*)d_ws;

    prep_kernel<<<dim3((DW_TOTAL + 255) / 256), dim3(256), 0, stream>>>(W1, W2, W3, W4, W5, ws);
    lpkt_kernel<<<dim3(BB), dim3(NTH), 0, stream>>>(
        e_data, a_data, it_data, at_data, qm, h0, Ee, Eat, Eit,
        W1, b1, W2, b2, W3, b3, W4, b4, W5, b5, out, ws);
}

// Round 7
// 1195.676 us; speedup vs baseline: 3.2448x; 3.2448x over previous
//
#include <hip/hip_runtime.h>
#include <hip/hip_fp16.h>
#include <math.h>

// LPKT restructured: everything input-dependent is precomputed as bulk GEMMs over
// all (b,t); the 99-step recurrent kernel (one WG of 512 thr per batch element)
// touches ~1 KB of global per step. Recurrent-path GEMV weights (W2d/W3d/W4l/W5b,
// 128 KB bf16) live permanently in registers distributed across the WG. h state
// (129x128 fp32) in registers (rows 0..127, MFMA C-layout, 4 cb over half-WGs) +
// row 128 in LDS (s_h128); gate matmul h@W4h on matrix cores (A-frags = 32 VGPR
// permanent); h row-128 logit computed from the same A-frags on VALU.
// amdgpu_waves_per_eu(2,2) pins the 256-VGPR budget (grid=64 -> 1 WG/CU anyway).

#define BB   64
#define SS   100
#define DK   128
#define NTH  512

// ws dword offsets
#define OFF_PW1AB   0          // 16384: W1 rows 0..255, k-pair packed, [s][d]
#define OFF_PW23ABC 16384      // 49152: [W2|W3] rows 0..383 -> cols 256, [s][j]
#define OFF_PW4I    65536      // 8192:  W4 rows 256..383, [s][j]
#define OFF_PW5A    73728      // 8192:  W5 rows 0..127, [s][j]
#define OFF_PW23D   81920      // 16384: [W2|W3] rows 384..511 per-thread slices
#define OFF_PW4L    98304      // 8192:  W4 rows 128..255 per-thread slices
#define OFF_PW5B    106496     // 8192:  W5 rows 128..255 per-thread slices
#define OFF_AFRAG   114688     // 8192:  W4h A-fragments
#define OFF_S1      122880     // 128:   colsum of W1 rows 256..383 (fp32 bits)
#define OFF_AL      123008     // 409600 dw: AL fp16 [6400][128]
#define OFF_PRE     532608     // 1638400 dw: PRE fp16 [6400][512]
#define WS_DW_TOTAL 2171008    // ~8.7 MB

typedef __attribute__((ext_vector_type(16))) float floatx16;
typedef __attribute__((ext_vector_type(8)))  short short8v;

__device__ __forceinline__ float frcp(float x) { return __builtin_amdgcn_rcpf(x); }
__device__ __forceinline__ float fsig(float x) { float t = __expf(-x); return frcp(1.0f + t); }
__device__ __forceinline__ float ftanh(float x) {
    x = fminf(20.0f, fmaxf(-20.0f, x));
    float t = __expf(-2.0f * x);
    return (1.0f - t) * frcp(1.0f + t);
}
__device__ __forceinline__ float rlf(float v, int s) {
    return __int_as_float(__builtin_amdgcn_readlane(__float_as_int(v), s));
}
__device__ __forceinline__ unsigned bfbits(float x) {
    unsigned u = __float_as_uint(x);
    return (u + 0x7fffu + ((u >> 16) & 1u)) >> 16;
}
__device__ __forceinline__ unsigned pack2(float a, float b) {
    return bfbits(a) | (bfbits(b) << 16);
}
__device__ __forceinline__ float blo(unsigned u) { return __uint_as_float(u << 16); }
__device__ __forceinline__ float bhi(unsigned u) { return __uint_as_float(u & 0xffff0000u); }

// ---- K0: weight packing ------------------------------------------------------
__global__ void k0_prep(const float* __restrict__ W1, const float* __restrict__ W2,
                        const float* __restrict__ W3, const float* __restrict__ W4,
                        const float* __restrict__ W5, unsigned* __restrict__ ws) {
    int g = blockIdx.x * blockDim.x + threadIdx.x;
    if (g < 16384) {                       // pw1ab
        int s = g >> 7, d = g & 127;
        ws[OFF_PW1AB + g] = pack2(W1[(2*s)*DK + d], W1[(2*s+1)*DK + d]);
    } else if (g < 65536) {                // pw23abc
        int i = g - 16384; int s = i >> 8, j = i & 255;
        const float* M = (j < 128) ? W2 : W3; int jj = j & 127;
        ws[g] = pack2(M[(2*s)*DK + jj], M[(2*s+1)*DK + jj]);
    } else if (g < 73728) {                // pw4i (W4 rows 256..383)
        int i = g - 65536; int s = i >> 7, j = i & 127;
        ws[g] = pack2(W4[(256+2*s)*DK + j], W4[(257+2*s)*DK + j]);
    } else if (g < 81920) {                // pw5a (W5 rows 0..127)
        int i = g - 73728; int s = i >> 7, j = i & 127;
        ws[g] = pack2(W5[(2*s)*DK + j], W5[(2*s+1)*DK + j]);
    } else if (g < 98304) {                // pw23d (rows 384..511), slice (kh,j1)
        int i = g - 81920; int s = i & 31, j = (i >> 5) & 255, kh = i >> 13;
        int k0 = 64*kh + 2*s;
        const float* M = (j < 128) ? W2 : W3; int jj = j & 127;
        ws[g] = pack2(M[(384+k0)*DK + jj], M[(385+k0)*DK + jj]);
    } else if (g < 106496) {               // pw4l (W4 rows 128..255), slice (kq,j3)
        int i = g - 98304; int s = i & 15, j = (i >> 4) & 127, kq = i >> 11;
        int k0 = 32*kq + 2*s;
        ws[g] = pack2(W4[(128+k0)*DK + j], W4[(129+k0)*DK + j]);
    } else if (g < 114688) {               // pw5b (W5 rows 128..255)
        int i = g - 106496; int s = i & 15, j = (i >> 4) & 127, kq = i >> 11;
        int k0 = 32*kq + 2*s;
        ws[g] = pack2(W5[(128+k0)*DK + j], W5[(129+k0)*DK + j]);
    } else if (g < 122880) {               // afrag: A[d=32g+m][k=16kb+8hp+2c,+1]
        int i = g - 114688;
        int gg = i >> 11, kb = (i >> 8) & 7, ln = (i >> 2) & 63, c = i & 3;
        int m = ln & 31, hp = ln >> 5;
        int k0 = 16*kb + 8*hp + 2*c;
        ws[g] = pack2(W4[k0*DK + 32*gg + m], W4[(k0+1)*DK + 32*gg + m]);
    } else if (g < 123008) {               // s1
        int d = g - 122880;
        float z = 0.f;
        for (int k = 0; k < 128; k++) z += W1[(256+k)*DK + d];
        ws[g] = __float_as_uint(z);
    }
}

// ---- K1: AL[b][t][:] = all_learning (fp16), t = 0..98 ------------------------
__global__ __launch_bounds__(128)
void k1_al(const int* __restrict__ e_data, const int* __restrict__ a_data,
           const int* __restrict__ at_data, const float* __restrict__ Ee,
           const float* __restrict__ Eat, const float* __restrict__ b1,
           unsigned* __restrict__ ws) {
    const int b = blockIdx.x, c = blockIdx.y, tid = threadIdx.x;
    __shared__ __align__(16) float s_f[4][256];
    #pragma unroll
    for (int r = 0; r < 8; r++) {
        int id = r * 128 + tid; int i = id >> 8, k = id & 255;
        int t = 4*c + i; float v = 0.f;
        if (t <= 98) {
            int e  = e_data[b*SS + t];
            int at = at_data[b*SS + t];
            v = (k < 128) ? Ee[(size_t)e*DK + k] : Eat[(size_t)at*DK + (k-128)];
        }
        s_f[i][k] = v;
    }
    __syncthreads();
    float s1v = __uint_as_float(ws[OFF_S1 + tid]);
    float b1v = b1[tid];
    float z0=0.f, z1=0.f, z2=0.f, z3=0.f;
    #pragma unroll 8
    for (int s = 0; s < 128; s++) {
        unsigned w = ws[OFF_PW1AB + s*128 + tid];
        float wl = blo(w), wh = bhi(w);
        float2 f;
        f = *(const float2*)&s_f[0][2*s]; z0 += f.x*wl + f.y*wh;
        f = *(const float2*)&s_f[1][2*s]; z1 += f.x*wl + f.y*wh;
        f = *(const float2*)&s_f[2][2*s]; z2 += f.x*wl + f.y*wh;
        f = *(const float2*)&s_f[3][2*s]; z3 += f.x*wl + f.y*wh;
    }
    __half* AL = (__half*)(ws + OFF_AL);
    float zz[4] = {z0, z1, z2, z3};
    #pragma unroll
    for (int i = 0; i < 4; i++) {
        int t = 4*c + i;
        if (t <= 98) {
            float a = (float)a_data[b*SS + t];
            AL[(size_t)(b*SS + t)*DK + tid] = __float2half(zz[i] + a*s1v + b1v);
        }
    }
}

// ---- K2: PRE[b][t][512] = [pre2|pre3|preC|preE] (fp16) -----------------------
__global__ __launch_bounds__(512)
void k2_pre(const int* __restrict__ e_data, const int* __restrict__ it_data,
            const float* __restrict__ Eit, const float* __restrict__ Ee,
            const float* __restrict__ b2, const float* __restrict__ b3,
            const float* __restrict__ b4, const float* __restrict__ b5,
            unsigned* __restrict__ ws) {
    const int b = blockIdx.x, c = blockIdx.y, tid = threadIdx.x;
    __shared__ __align__(16) float s_g[4][384];
    __shared__ __align__(16) float s_e[4][128];
    const __half* AL = (const __half*)(ws + OFF_AL);
    #pragma unroll
    for (int r = 0; r < 3; r++) {
        int id = r * 512 + tid; int i = id / 384; int k = id - 384*i;
        int t = 4*c + i; float v = 0.f;
        if (t <= 98) {
            if (k < 128)      v = (t == 0) ? 0.f : (float)AL[(size_t)(b*SS + t - 1)*DK + k];
            else if (k < 256) v = Eit[(size_t)it_data[b*SS + t]*DK + (k - 128)];
            else              v = (float)AL[(size_t)(b*SS + t)*DK + (k - 256)];
        }
        s_g[i][k] = v;
    }
    {   int i = tid >> 7, k = tid & 127; int t = 4*c + i;
        s_e[i][k] = (t <= 98) ? Ee[(size_t)e_data[b*SS + t + 1]*DK + k] : 0.f; }
    __syncthreads();
    __half* PRE = (__half*)(ws + OFF_PRE);
    float z0=0.f, z1=0.f, z2=0.f, z3=0.f;
    int col, bias_done = 0; float bb = 0.f;
    if (tid < 256) {
        int j = tid;
        #pragma unroll 8
        for (int s = 0; s < 192; s++) {
            unsigned w = ws[OFF_PW23ABC + s*256 + j];
            float wl = blo(w), wh = bhi(w);
            float2 f;
            f = *(const float2*)&s_g[0][2*s]; z0 += f.x*wl + f.y*wh;
            f = *(const float2*)&s_g[1][2*s]; z1 += f.x*wl + f.y*wh;
            f = *(const float2*)&s_g[2][2*s]; z2 += f.x*wl + f.y*wh;
            f = *(const float2*)&s_g[3][2*s]; z3 += f.x*wl + f.y*wh;
        }
        col = j; bb = (j < 128) ? b2[j] : b3[j - 128]; bias_done = 1;
    } else if (tid < 384) {
        int j = tid - 256;
        #pragma unroll 8
        for (int s = 0; s < 64; s++) {
            unsigned w = ws[OFF_PW4I + s*128 + j];
            float wl = blo(w), wh = bhi(w);
            float2 f;
            f = *(const float2*)&s_g[0][128 + 2*s]; z0 += f.x*wl + f.y*wh;
            f = *(const float2*)&s_g[1][128 + 2*s]; z1 += f.x*wl + f.y*wh;
            f = *(const float2*)&s_g[2][128 + 2*s]; z2 += f.x*wl + f.y*wh;
            f = *(const float2*)&s_g[3][128 + 2*s]; z3 += f.x*wl + f.y*wh;
        }
        col = 256 + j; bb = b4[j]; bias_done = 1;
    } else {
        int j = tid - 384;
        #pragma unroll 8
        for (int s = 0; s < 64; s++) {
            unsigned w = ws[OFF_PW5A + s*128 + j];
            float wl = blo(w), wh = bhi(w);
            float2 f;
            f = *(const float2*)&s_e[0][2*s]; z0 += f.x*wl + f.y*wh;
            f = *(const float2*)&s_e[1][2*s]; z1 += f.x*wl + f.y*wh;
            f = *(const float2*)&s_e[2][2*s]; z2 += f.x*wl + f.y*wh;
            f = *(const float2*)&s_e[3][2*s]; z3 += f.x*wl + f.y*wh;
        }
        col = 384 + j; bb = b5[j]; bias_done = 1;
    }
    (void)bias_done;
    float zz[4] = {z0, z1, z2, z3};
    #pragma unroll
    for (int i = 0; i < 4; i++) {
        int t = 4*c + i;
        if (t <= 98) PRE[(size_t)(b*SS + t)*512 + col] = __float2half(zz[i] + bb);
    }
}

// ---- K3: recurrent kernel ----------------------------------------------------
__global__ __launch_bounds__(NTH)
__attribute__((amdgpu_waves_per_eu(2, 2)))
void lpkt_kernel(const int* __restrict__ e_data, const float* __restrict__ qm,
                 const float* __restrict__ h0, float* __restrict__ out,
                 const unsigned* __restrict__ ws)
{
    const int b    = blockIdx.x;
    const int tid  = threadIdx.x;
    const int lane = tid & 63;
    const int w    = tid >> 6;
    const int g    = w & 3;            // MFMA d-block
    const int hh   = w >> 2;           // half: cb pair {2hh, 2hh+1}; P1 k-half
    const int h5   = lane >> 5;
    const int l31  = lane & 31;
    const int kq   = w >> 1;           // P3/P6 k-quarter
    const int j1   = tid & 255;        // P1 output col (z2: j1<128, z3: j1>=128)
    const int j3   = tid & 127;        // P3/P6 output col

    __shared__ __align__(16) unsigned s_frag[8192];   // 32 KB: (kb*4+cb) 1KB blocks
    __shared__ __align__(16) float s_pre[2][512];
    __shared__ __align__(16) float s_htv[128];
    __shared__ __align__(16) float s_LG[128];
    __shared__ __align__(16) float s_h128[128];
    __shared__ __align__(16) float s_c[128];
    __shared__ __align__(16) float s_l128[128];
    __shared__ __align__(16) float s_red[512];
    __shared__ __align__(16) float s_redE[512];
    __shared__ float s_ht2[2][128];
    __shared__ float s_q[2][160];
    __shared__ float s_scal[1];

    // ---- permanent registers ----
    uint4    afru[8];
    unsigned w23[32], w4l[16], w5b[16];
    float    hreg[2][16];

    #pragma unroll
    for (int kb = 0; kb < 8; kb++)
        afru[kb] = ((const uint4*)(ws + OFF_AFRAG))[g*512 + kb*64 + lane];
    #pragma unroll
    for (int s = 0; s < 32; s++) w23[s] = ws[OFF_PW23D + ((hh*256 + j1) << 5) + s];
    #pragma unroll
    for (int s = 0; s < 16; s++) w4l[s] = ws[OFF_PW4L + ((kq*128 + j3) << 4) + s];
    #pragma unroll
    for (int s = 0; s < 16; s++) w5b[s] = ws[OFF_PW5B + ((kq*128 + j3) << 4) + s];

    // ---- prologue: h0 -> hreg + fragments; q0; ht0 ----
    #pragma unroll
    for (int i = 0; i < 2; i++) {
        const int cb = 2*hh + i;
        const int n = 32*cb + l31;
        #pragma unroll
        for (int r = 0; r < 16; r++) {
            int d = 32*g + (r&3) + 8*(r>>2) + 4*h5;
            hreg[i][r] = h0[(size_t)n*DK + d];
        }
        #pragma unroll
        for (int q = 0; q < 4; q++) {
            int kb = 2*g + (q>>1);
            int lanep = l31 + ((q&1) << 5);
            int off = (((kb*4 + cb) << 10) + lanep*16 + (h5 << 3)) >> 2;
            s_frag[off]   = pack2(hreg[i][4*q],   hreg[i][4*q+1]);
            s_frag[off+1] = pack2(hreg[i][4*q+2], hreg[i][4*q+3]);
        }
    }
    if (tid < 128) s_h128[tid] = h0[(size_t)128*DK + tid];
    if (tid < 160) {
        int e0 = e_data[b*SS];
        s_q[0][tid] = (tid < 129) ? qm[(size_t)e0*129 + tid] : 0.f;
    }
    if (tid == 0) out[b*SS] = 0.f;
    __syncthreads();
    if (w == 7) {
        float v = s_q[0][lane] + s_q[0][64+lane] + ((lane < 32) ? s_q[0][128+lane] : 0.f);
        #pragma unroll
        for (int m = 32; m > 0; m >>= 1) v += __shfl_xor(v, m);
        if (lane == 0) s_scal[0] = v;
    }
    __syncthreads();
    {
        float ph[16];
        #pragma unroll
        for (int r = 0; r < 16; r++) ph[r] = 0.f;
        #pragma unroll
        for (int i = 0; i < 2; i++) {
            float qv = s_q[0][32*(2*hh + i) + l31];
            #pragma unroll
            for (int r = 0; r < 16; r++) ph[r] += qv * hreg[i][r];
        }
        #pragma unroll
        for (int r = 0; r < 16; r++) {
            float v = ph[r];
            v += __shfl_xor(v,1); v += __shfl_xor(v,2); v += __shfl_xor(v,4);
            v += __shfl_xor(v,8); v += __shfl_xor(v,16);
            if (l31 == 0) s_ht2[hh][32*g + (r&3) + 8*(r>>2) + 4*h5] = v;
        }
    }
    __syncthreads();
    if (tid < 128)
        s_htv[tid] = (s_ht2[0][tid] + s_ht2[1][tid] + s_q[0][128]*s_h128[tid]) * frcp(s_scal[0]);
    __syncthreads();

    const __half* PRE = (const __half*)(ws + OFF_PRE);

    // ---- recurrence ----
    for (int t = 0; t < SS - 1; t++) {
        const int pb = t & 1;
        const float* qc = s_q[pb];
        float*       qn = s_q[1 - pb];
        const __half* pp = PRE + (size_t)(b*SS + t)*512;

        // ph1: stage pre + q_next; P1 = htp . [W2d|W3d]
        {
            s_pre[pb][tid] = __half2float(pp[tid]);
            if (tid < 160) {
                int e_nx = e_data[b*SS + t + 1];
                qn[tid] = (tid < 129) ? qm[(size_t)e_nx*129 + tid] : 0.f;
            }
            float4 fv = ((const float4*)s_htv)[(hh << 4) + (l31 & 15)];
            float z = 0.f;
            #pragma unroll
            for (int s = 0; s < 16; s++) {
                float a0 = rlf(fv.x, s), a1 = rlf(fv.y, s);
                float a2 = rlf(fv.z, s), a3 = rlf(fv.w, s);
                z += a0*blo(w23[2*s])   + a1*bhi(w23[2*s]);
                z += a2*blo(w23[2*s+1]) + a3*bhi(w23[2*s+1]);
            }
            s_red[(hh << 8) + j1] = z;
        }
        __syncthreads();   // B1
        // ph2: LG; wave7: q_next sum
        if (tid < 128) {
            float z2 = s_red[tid]       + s_red[256 + tid] + s_pre[pb][tid];
            float z3 = s_red[128 + tid] + s_red[384 + tid] + s_pre[pb][128 + tid];
            s_LG[tid] = fsig(z3) * (ftanh(z2) + 1.f) * 0.5f;
        }
        if (w == 7) {
            float v = qn[lane] + qn[64+lane] + ((lane < 32) ? qn[128+lane] : 0.f);
            #pragma unroll
            for (int m = 32; m > 0; m >>= 1) v += __shfl_xor(v, m);
            if (lane == 0) s_scal[0] = v;
        }
        __syncthreads();   // B2
        // ph3: P3 = LG . W4l
        {
            float4 fv = ((const float4*)s_LG)[(kq << 3) + (l31 & 7)];
            float z = 0.f;
            #pragma unroll
            for (int s = 0; s < 8; s++) {
                float a0 = rlf(fv.x, s), a1 = rlf(fv.y, s);
                float a2 = rlf(fv.z, s), a3 = rlf(fv.w, s);
                z += a0*blo(w4l[2*s])   + a1*bhi(w4l[2*s]);
                z += a2*blo(w4l[2*s+1]) + a3*bhi(w4l[2*s+1]);
            }
            s_red[(kq << 7) + j3] = z;
        }
        __syncthreads();   // B3
        if (tid < 128)
            s_c[tid] = s_red[tid] + s_red[128+tid] + s_red[256+tid] + s_red[384+tid]
                     + s_pre[pb][256 + tid];
        __syncthreads();   // B4
        // ph5: MFMA + gates (acc transient per cb) + row-128 logit from afr
        float ph[16];
        #pragma unroll
        for (int r = 0; r < 16; r++) ph[r] = 0.f;
        float hnew128 = 0.f;
        {
            #pragma unroll
            for (int i = 0; i < 2; i++) {
                const int cb = 2*hh + i;
                floatx16 a = (floatx16)(0.f);
                #pragma unroll
                for (int kb = 0; kb < 8; kb++) {
                    short8v bf = *(const short8v*)((const char*)s_frag +
                                   (((kb*4 + cb) << 10) + lane*16));
                    a = __builtin_amdgcn_mfma_f32_32x32x16_bf16(
                            __builtin_bit_cast(short8v, afru[kb]), bf, a, 0, 0, 0);
                }
                const int n = 32*cb + l31;
                const float qcv = qc[n], qnv = qn[n];
                #pragma unroll
                for (int r = 0; r < 16; r++) {
                    const int d = 32*g + (r&3) + 8*(r>>2) + 4*h5;
                    float gg = fsig(a[r] + s_c[d]);
                    float hn = qcv*s_LG[d] + gg*hreg[i][r];
                    hreg[i][r] = hn;
                    ph[r] += qnv*hn;
                }
            }
            if (hh == 0) {   // logit for h row 128 via A-fragments (VALU)
                float part = 0.f;
                #pragma unroll
                for (int kb = 0; kb < 8; kb++) {
                    int kb0 = 16*kb + 8*h5;
                    uint4 u = afru[kb];
                    part += s_h128[kb0+0]*blo(u.x) + s_h128[kb0+1]*bhi(u.x);
                    part += s_h128[kb0+2]*blo(u.y) + s_h128[kb0+3]*bhi(u.y);
                    part += s_h128[kb0+4]*blo(u.z) + s_h128[kb0+5]*bhi(u.z);
                    part += s_h128[kb0+6]*blo(u.w) + s_h128[kb0+7]*bhi(u.w);
                }
                part += __shfl_xor(part, 32);
                if (h5 == 0) s_l128[32*g + l31] = part;
            }
        }
        __syncthreads();   // B5 (all frag/s_h128 reads done; s_l128 ready)
        // ph6: fragment rewrite + h_tilde partials + h row-128 update
        {
            #pragma unroll
            for (int i = 0; i < 2; i++) {
                const int cb = 2*hh + i;
                #pragma unroll
                for (int q = 0; q < 4; q++) {
                    int kb = 2*g + (q>>1);
                    int lanep = l31 + ((q&1) << 5);
                    int off = (((kb*4 + cb) << 10) + lanep*16 + (h5 << 3)) >> 2;
                    s_frag[off]   = pack2(hreg[i][4*q],   hreg[i][4*q+1]);
                    s_frag[off+1] = pack2(hreg[i][4*q+2], hreg[i][4*q+3]);
                }
            }
            #pragma unroll
            for (int r = 0; r < 16; r++) {
                float v = ph[r];
                v += __shfl_xor(v,1); v += __shfl_xor(v,2); v += __shfl_xor(v,4);
                v += __shfl_xor(v,8); v += __shfl_xor(v,16);
                if (l31 == 0) s_ht2[hh][32*g + (r&3) + 8*(r>>2) + 4*h5] = v;
            }
            if (tid < 128) {
                float gg = fsig(s_l128[tid] + s_c[tid]);
                hnew128 = qc[128]*s_LG[tid] + gg*s_h128[tid];
                s_h128[tid] = hnew128;
            }
        }
        __syncthreads();   // B6
        if (tid < 128)
            s_htv[tid] = (s_ht2[0][tid] + s_ht2[1][tid] + qn[128]*hnew128) * frcp(s_scal[0]);
        __syncthreads();   // B7
        // ph8: P6 = h_tilde . W5b
        {
            float4 fv = ((const float4*)s_htv)[(kq << 3) + (l31 & 7)];
            float z = 0.f;
            #pragma unroll
            for (int s = 0; s < 8; s++) {
                float a0 = rlf(fv.x, s), a1 = rlf(fv.y, s);
                float a2 = rlf(fv.z, s), a3 = rlf(fv.w, s);
                z += a0*blo(w5b[2*s])   + a1*bhi(w5b[2*s]);
                z += a2*blo(w5b[2*s+1]) + a3*bhi(w5b[2*s+1]);
            }
            s_redE[(kq << 7) + j3] = z;
        }
        __syncthreads();   // B8
        // ph9: y
        if (tid < 64) {
            float va = s_redE[lane]    + s_redE[128+lane] + s_redE[256+lane] + s_redE[384+lane]
                     + s_pre[pb][384 + lane];
            float vb = s_redE[64+lane] + s_redE[192+lane] + s_redE[320+lane] + s_redE[448+lane]
                     + s_pre[pb][448 + lane];
            float v = fsig(va) + fsig(vb);
            #pragma unroll
            for (int m = 32; m > 0; m >>= 1) v += __shfl_xor(v, m);
            if (lane == 0) out[b*SS + t + 1] = v * (1.0f / 128.0f);
        }
        // no trailing barrier: ph9 reads s_redE/s_pre[pb]; next ph1 writes
        // s_red/s_pre[1-pb]/s_q[pb] (qc dead after B6) — disjoint.
    }
}

extern "C" void kernel_launch(void* const* d_in, const int* in_sizes, int n_in,
                              void* d_out, int out_size, void* d_ws, size_t ws_size,
                              hipStream_t stream) {
    const int*   e_data  = (const int*)d_in[0];
    const int*   a_data  = (const int*)d_in[1];
    const int*   it_data = (const int*)d_in[2];
    const int*   at_data = (const int*)d_in[3];
    const float* qm  = (const float*)d_in[4];
    const float* h0  = (const float*)d_in[5];
    const float* Ee  = (const float*)d_in[6];
    const float* Eat = (const float*)d_in[7];
    const float* Eit = (const float*)d_in[8];
    const float* W1  = (const float*)d_in[9];
    const float* b1  = (const float*)d_in[10];
    const float* W2  = (const float*)d_in[11];
    const float* b2  = (const float*)d_in[12];
    const float* W3  = (const float*)d_in[13];
    const float* b3  = (const float*)d_in[14];
    const float* W4  = (const float*)d_in[15];
    const float* b4  = (const float*)d_in[16];
    const float* W5  = (const float*)d_in[17];
    const float* b5  = (const float*)d_in[18];
    float* out = (float*)d_out;
    unsigned* ws = (unsigned*)d_ws;

    k0_prep<<<dim3((123008 + 255) / 256), dim3(256), 0, stream>>>(W1, W2, W3, W4, W5, ws);
    k1_al<<<dim3(BB, 25), dim3(128), 0, stream>>>(e_data, a_data, at_data, Ee, Eat, b1, ws);
    k2_pre<<<dim3(BB, 25), dim3(512), 0, stream>>>(e_data, it_data, Eit, Ee, b2, b3, b4, b5, ws);
    lpkt_kernel<<<dim3(BB), dim3(NTH), 0, stream>>>(e_data, qm, h0, out, ws);
}

// Round 8
// 941.368 us; speedup vs baseline: 4.1214x; 1.2701x over previous
//
#include <hip/hip_runtime.h>
#include <hip/hip_fp16.h>
#include <math.h>

// LPKT: precompute-everything structure (R7) + register/reduction fixes (R8).
// K0 packs weights; K1/K2 precompute AL / PRE = all input-dependent GEMV parts
// as bulk GEMMs (t-tiled 16/block to amortize weight reads). The recurrent kernel
// (one WG of 512 thr per batch element) holds h (rows 0..127) in registers in MFMA
// C-layout (4 cb over half-WGs), row 128 in LDS; recurrent GEMV weights
// (W2d/W3d/W4l/W5b) permanently in registers; gate matmul h@W4h on matrix cores.
// R8: __launch_bounds__(512,2) -> 256-VGPR budget (R7's waves_per_eu attr capped
// at 128 == permanent count -> 7.3MB spill traffic); shuffle-butterfly h-tilde
// reductions replaced by padded-LDS scatter/gather (s_big[2][128][33]); 4-acc GEMVs.

#define BB   64
#define SS   100
#define DK   128
#define NTH  512

// ws dword offsets (same map as R7)
#define OFF_PW1AB   0
#define OFF_PW23ABC 16384
#define OFF_PW4I    65536
#define OFF_PW5A    73728
#define OFF_PW23D   81920
#define OFF_PW4L    98304
#define OFF_PW5B    106496
#define OFF_AFRAG   114688
#define OFF_S1      122880
#define OFF_AL      123008
#define OFF_PRE     532608

typedef __attribute__((ext_vector_type(16))) float floatx16;
typedef __attribute__((ext_vector_type(8)))  short short8v;

__device__ __forceinline__ float frcp(float x) { return __builtin_amdgcn_rcpf(x); }
__device__ __forceinline__ float fsig(float x) { float t = __expf(-x); return frcp(1.0f + t); }
__device__ __forceinline__ float ftanh(float x) {
    x = fminf(20.0f, fmaxf(-20.0f, x));
    float t = __expf(-2.0f * x);
    return (1.0f - t) * frcp(1.0f + t);
}
__device__ __forceinline__ float rlf(float v, int s) {
    return __int_as_float(__builtin_amdgcn_readlane(__float_as_int(v), s));
}
__device__ __forceinline__ unsigned bfbits(float x) {
    unsigned u = __float_as_uint(x);
    return (u + 0x7fffu + ((u >> 16) & 1u)) >> 16;
}
__device__ __forceinline__ unsigned pack2(float a, float b) {
    return bfbits(a) | (bfbits(b) << 16);
}
__device__ __forceinline__ float blo(unsigned u) { return __uint_as_float(u << 16); }
__device__ __forceinline__ float bhi(unsigned u) { return __uint_as_float(u & 0xffff0000u); }

// ---- K0: weight packing (unchanged from R7) ----------------------------------
__global__ void k0_prep(const float* __restrict__ W1, const float* __restrict__ W2,
                        const float* __restrict__ W3, const float* __restrict__ W4,
                        const float* __restrict__ W5, unsigned* __restrict__ ws) {
    int g = blockIdx.x * blockDim.x + threadIdx.x;
    if (g < 16384) {
        int s = g >> 7, d = g & 127;
        ws[OFF_PW1AB + g] = pack2(W1[(2*s)*DK + d], W1[(2*s+1)*DK + d]);
    } else if (g < 65536) {
        int i = g - 16384; int s = i >> 8, j = i & 255;
        const float* M = (j < 128) ? W2 : W3; int jj = j & 127;
        ws[g] = pack2(M[(2*s)*DK + jj], M[(2*s+1)*DK + jj]);
    } else if (g < 73728) {
        int i = g - 65536; int s = i >> 7, j = i & 127;
        ws[g] = pack2(W4[(256+2*s)*DK + j], W4[(257+2*s)*DK + j]);
    } else if (g < 81920) {
        int i = g - 73728; int s = i >> 7, j = i & 127;
        ws[g] = pack2(W5[(2*s)*DK + j], W5[(2*s+1)*DK + j]);
    } else if (g < 98304) {
        int i = g - 81920; int s = i & 31, j = (i >> 5) & 255, kh = i >> 13;
        int k0 = 64*kh + 2*s;
        const float* M = (j < 128) ? W2 : W3; int jj = j & 127;
        ws[g] = pack2(M[(384+k0)*DK + jj], M[(385+k0)*DK + jj]);
    } else if (g < 106496) {
        int i = g - 98304; int s = i & 15, j = (i >> 4) & 127, kq = i >> 11;
        int k0 = 32*kq + 2*s;
        ws[g] = pack2(W4[(128+k0)*DK + j], W4[(129+k0)*DK + j]);
    } else if (g < 114688) {
        int i = g - 106496; int s = i & 15, j = (i >> 4) & 127, kq = i >> 11;
        int k0 = 32*kq + 2*s;
        ws[g] = pack2(W5[(128+k0)*DK + j], W5[(129+k0)*DK + j]);
    } else if (g < 122880) {
        int i = g - 114688;
        int gg = i >> 11, kb = (i >> 8) & 7, ln = (i >> 2) & 63, c = i & 3;
        int m = ln & 31, hp = ln >> 5;
        int k0 = 16*kb + 8*hp + 2*c;
        ws[g] = pack2(W4[k0*DK + 32*gg + m], W4[(k0+1)*DK + 32*gg + m]);
    } else if (g < 123008) {
        int d = g - 122880;
        float z = 0.f;
        for (int k = 0; k < 128; k++) z += W1[(256+k)*DK + d];
        ws[g] = __float_as_uint(z);
    }
}

// ---- K1: AL (fp16), 16 timesteps per block -----------------------------------
__global__ __launch_bounds__(128)
void k1_al(const int* __restrict__ e_data, const int* __restrict__ a_data,
           const int* __restrict__ at_data, const float* __restrict__ Ee,
           const float* __restrict__ Eat, const float* __restrict__ b1,
           unsigned* __restrict__ ws) {
    const int b = blockIdx.x, t0 = 16 * blockIdx.y, tid = threadIdx.x;
    __shared__ __align__(16) float s_f[16][256];
    #pragma unroll
    for (int r = 0; r < 32; r++) {
        int id = r * 128 + tid; int i = id >> 8, k = id & 255;
        int t = t0 + i; float v = 0.f;
        if (t <= 98) {
            int e  = e_data[b*SS + t];
            int at = at_data[b*SS + t];
            v = (k < 128) ? Ee[(size_t)e*DK + k] : Eat[(size_t)at*DK + (k-128)];
        }
        s_f[i][k] = v;
    }
    __syncthreads();
    float s1v = __uint_as_float(ws[OFF_S1 + tid]);
    float b1v = b1[tid];
    float z[16];
    #pragma unroll
    for (int i = 0; i < 16; i++) z[i] = 0.f;
    #pragma unroll 2
    for (int s = 0; s < 128; s++) {
        unsigned w = ws[OFF_PW1AB + s*128 + tid];
        float wl = blo(w), wh = bhi(w);
        #pragma unroll
        for (int i = 0; i < 16; i++) {
            float2 f = *(const float2*)&s_f[i][2*s];
            z[i] += f.x*wl + f.y*wh;
        }
    }
    __half* AL = (__half*)(ws + OFF_AL);
    #pragma unroll
    for (int i = 0; i < 16; i++) {
        int t = t0 + i;
        if (t <= 98) {
            float a = (float)a_data[b*SS + t];
            AL[(size_t)(b*SS + t)*DK + tid] = __float2half(z[i] + a*s1v + b1v);
        }
    }
}

// ---- K2: PRE[b][t][512] (fp16), 16 timesteps per block -----------------------
__global__ __launch_bounds__(512)
void k2_pre(const int* __restrict__ e_data, const int* __restrict__ it_data,
            const float* __restrict__ Eit, const float* __restrict__ Ee,
            const float* __restrict__ b2, const float* __restrict__ b3,
            const float* __restrict__ b4, const float* __restrict__ b5,
            unsigned* __restrict__ ws) {
    const int b = blockIdx.x, t0 = 16 * blockIdx.y, tid = threadIdx.x;
    __shared__ __align__(16) float s_g[16][384];
    __shared__ __align__(16) float s_e[16][128];
    const __half* AL = (const __half*)(ws + OFF_AL);
    #pragma unroll
    for (int r = 0; r < 12; r++) {
        int id = r * 512 + tid; int i = id / 384; int k = id - 384*i;
        int t = t0 + i; float v = 0.f;
        if (t <= 98) {
            if (k < 128)      v = (t == 0) ? 0.f : (float)AL[(size_t)(b*SS + t - 1)*DK + k];
            else if (k < 256) v = Eit[(size_t)it_data[b*SS + t]*DK + (k - 128)];
            else              v = (float)AL[(size_t)(b*SS + t)*DK + (k - 256)];
        }
        s_g[i][k] = v;
    }
    #pragma unroll
    for (int r = 0; r < 4; r++) {
        int id = r * 512 + tid; int i = id >> 7, k = id & 127;
        int t = t0 + i;
        s_e[i][k] = (t <= 98) ? Ee[(size_t)e_data[b*SS + t + 1]*DK + k] : 0.f;
    }
    __syncthreads();
    __half* PRE = (__half*)(ws + OFF_PRE);
    float z[16];
    #pragma unroll
    for (int i = 0; i < 16; i++) z[i] = 0.f;
    int col; float bb;
    if (tid < 256) {
        int j = tid;
        #pragma unroll 2
        for (int s = 0; s < 192; s++) {
            unsigned w = ws[OFF_PW23ABC + s*256 + j];
            float wl = blo(w), wh = bhi(w);
            #pragma unroll
            for (int i = 0; i < 16; i++) {
                float2 f = *(const float2*)&s_g[i][2*s];
                z[i] += f.x*wl + f.y*wh;
            }
        }
        col = j; bb = (j < 128) ? b2[j] : b3[j - 128];
    } else if (tid < 384) {
        int j = tid - 256;
        #pragma unroll 2
        for (int s = 0; s < 64; s++) {
            unsigned w = ws[OFF_PW4I + s*128 + j];
            float wl = blo(w), wh = bhi(w);
            #pragma unroll
            for (int i = 0; i < 16; i++) {
                float2 f = *(const float2*)&s_g[i][128 + 2*s];
                z[i] += f.x*wl + f.y*wh;
            }
        }
        col = 256 + j; bb = b4[j];
    } else {
        int j = tid - 384;
        #pragma unroll 2
        for (int s = 0; s < 64; s++) {
            unsigned w = ws[OFF_PW5A + s*128 + j];
            float wl = blo(w), wh = bhi(w);
            #pragma unroll
            for (int i = 0; i < 16; i++) {
                float2 f = *(const float2*)&s_e[i][2*s];
                z[i] += f.x*wl + f.y*wh;
            }
        }
        col = 384 + j; bb = b5[j];
    }
    #pragma unroll
    for (int i = 0; i < 16; i++) {
        int t = t0 + i;
        if (t <= 98) PRE[(size_t)(b*SS + t)*512 + col] = __float2half(z[i] + bb);
    }
}

// ---- K3: recurrent kernel ----------------------------------------------------
__global__ __launch_bounds__(NTH, 2)
void lpkt_kernel(const int* __restrict__ e_data, const float* __restrict__ qm,
                 const float* __restrict__ h0, float* __restrict__ out,
                 const unsigned* __restrict__ ws)
{
    const int b    = blockIdx.x;
    const int tid  = threadIdx.x;
    const int lane = tid & 63;
    const int w    = tid >> 6;
    const int g    = w & 3;            // MFMA d-block
    const int hh   = w >> 2;           // half: cb pair {2hh, 2hh+1}; P1 k-half
    const int h5   = lane >> 5;
    const int l31  = lane & 31;
    const int kq   = w >> 1;           // P3/P6 k-quarter
    const int j1   = tid & 255;        // P1 output col
    const int j3   = tid & 127;        // P3/P6 output col

    __shared__ __align__(16) unsigned s_frag[8192];   // 32 KB B-fragments
    __shared__ __align__(16) float s_big[2 * 128 * 33]; // padded ht-reduce scratch
    __shared__ __align__(16) float s_pre[2][512];
    __shared__ __align__(16) float s_htv[128];
    __shared__ __align__(16) float s_LG[128];
    __shared__ __align__(16) float s_h128[128];
    __shared__ __align__(16) float s_c[128];
    __shared__ __align__(16) float s_l128[128];
    __shared__ __align__(16) float s_red[512];
    __shared__ __align__(16) float s_redE[512];
    __shared__ float s_q[2][160];
    __shared__ float s_scal[1];

    // ---- permanent registers (128): afru 32 + w23 32 + w4l/w5b 32 + hreg 32 ----
    uint4    afru[8];
    unsigned w23[32], w4l[16], w5b[16];
    float    hreg[2][16];

    #pragma unroll
    for (int kb = 0; kb < 8; kb++)
        afru[kb] = ((const uint4*)(ws + OFF_AFRAG))[g*512 + kb*64 + lane];
    #pragma unroll
    for (int s = 0; s < 32; s++) w23[s] = ws[OFF_PW23D + ((hh*256 + j1) << 5) + s];
    #pragma unroll
    for (int s = 0; s < 16; s++) w4l[s] = ws[OFF_PW4L + ((kq*128 + j3) << 4) + s];
    #pragma unroll
    for (int s = 0; s < 16; s++) w5b[s] = ws[OFF_PW5B + ((kq*128 + j3) << 4) + s];

    // ---- prologue ----
    #pragma unroll
    for (int i = 0; i < 2; i++) {
        const int cb = 2*hh + i;
        const int n = 32*cb + l31;
        #pragma unroll
        for (int r = 0; r < 16; r++) {
            int d = 32*g + (r&3) + 8*(r>>2) + 4*h5;
            hreg[i][r] = h0[(size_t)n*DK + d];
        }
        #pragma unroll
        for (int q = 0; q < 4; q++) {
            int kb = 2*g + (q>>1);
            int lanep = l31 + ((q&1) << 5);
            int off = (((kb*4 + cb) << 10) + lanep*16 + (h5 << 3)) >> 2;
            uint2 pr = make_uint2(pack2(hreg[i][4*q],   hreg[i][4*q+1]),
                                  pack2(hreg[i][4*q+2], hreg[i][4*q+3]));
            *(uint2*)(s_frag + off) = pr;
        }
    }
    if (tid < 128) s_h128[tid] = h0[(size_t)128*DK + tid];
    if (tid < 160) {
        int e0 = e_data[b*SS];
        s_q[0][tid] = (tid < 129) ? qm[(size_t)e0*129 + tid] : 0.f;
    }
    if (tid == 0) out[b*SS] = 0.f;
    __syncthreads();
    {   // vv0 -> s_big ; wave7: q0 sum
        if (w == 7) {
            float v = s_q[0][lane] + s_q[0][64+lane] + ((lane < 32) ? s_q[0][128+lane] : 0.f);
            #pragma unroll
            for (int m = 32; m > 0; m >>= 1) v += __shfl_xor(v, m);
            if (lane == 0) s_scal[0] = v;
        }
        float vv0[16];
        #pragma unroll
        for (int i = 0; i < 2; i++) {
            float qv = s_q[0][32*(2*hh + i) + l31];
            #pragma unroll
            for (int r = 0; r < 16; r++) {
                float p = qv * hreg[i][r];
                vv0[r] = i ? (vv0[r] + p) : p;
            }
        }
        #pragma unroll
        for (int r = 0; r < 16; r++) {
            int d = 32*g + (r&3) + 8*(r>>2) + 4*h5;
            s_big[(hh*128 + d)*33 + l31] = vv0[r];
        }
    }
    __syncthreads();
    if (tid < 128) {
        float a0 = 0.f, a1 = 0.f;
        #pragma unroll 8
        for (int j = 0; j < 32; j++) {
            a0 += s_big[tid*33 + j];
            a1 += s_big[(128 + tid)*33 + j];
        }
        s_htv[tid] = (a0 + a1 + s_q[0][128]*s_h128[tid]) * frcp(s_scal[0]);
    }
    __syncthreads();

    const __half* PRE = (const __half*)(ws + OFF_PRE);

    // ---- recurrence ----
    for (int t = 0; t < SS - 1; t++) {
        const int pb = t & 1;
        const float* qc = s_q[pb];
        float*       qn = s_q[1 - pb];
        const __half* pp = PRE + (size_t)(b*SS + t)*512;

        // ph1: stage pre + q_next; P1 = htp . [W2d|W3d] (4-acc)
        {
            s_pre[pb][tid] = __half2float(pp[tid]);
            if (tid < 160) {
                int e_nx = e_data[b*SS + t + 1];
                qn[tid] = (tid < 129) ? qm[(size_t)e_nx*129 + tid] : 0.f;
            }
            float4 fv = ((const float4*)s_htv)[(hh << 4) + (l31 & 15)];
            float z0 = 0.f, z1 = 0.f, z2 = 0.f, z3 = 0.f;
            #pragma unroll
            for (int s = 0; s < 16; s++) {
                float a0 = rlf(fv.x, s), a1 = rlf(fv.y, s);
                float a2 = rlf(fv.z, s), a3 = rlf(fv.w, s);
                unsigned wA = w23[2*s], wB = w23[2*s+1];
                z0 += a0*blo(wA);  z1 += a1*bhi(wA);
                z2 += a2*blo(wB);  z3 += a3*bhi(wB);
            }
            s_red[(hh << 8) + j1] = (z0 + z1) + (z2 + z3);
        }
        __syncthreads();   // B1
        // ph2: LG (t<128); wave7 q_next sum
        if (tid < 128) {
            float z2 = s_red[tid]       + s_red[256 + tid] + s_pre[pb][tid];
            float z3 = s_red[128 + tid] + s_red[384 + tid] + s_pre[pb][128 + tid];
            s_LG[tid] = fsig(z3) * (ftanh(z2) + 1.f) * 0.5f;
        }
        if (w == 7) {
            float v = qn[lane] + qn[64+lane] + ((lane < 32) ? qn[128+lane] : 0.f);
            #pragma unroll
            for (int m = 32; m > 0; m >>= 1) v += __shfl_xor(v, m);
            if (lane == 0) s_scal[0] = v;
        }
        __syncthreads();   // B2
        // ph3: P3 = LG . W4l (4-acc)
        {
            float4 fv = ((const float4*)s_LG)[(kq << 3) + (l31 & 7)];
            float z0 = 0.f, z1 = 0.f, z2 = 0.f, z3 = 0.f;
            #pragma unroll
            for (int s = 0; s < 8; s++) {
                float a0 = rlf(fv.x, s), a1 = rlf(fv.y, s);
                float a2 = rlf(fv.z, s), a3 = rlf(fv.w, s);
                unsigned wA = w4l[2*s], wB = w4l[2*s+1];
                z0 += a0*blo(wA);  z1 += a1*bhi(wA);
                z2 += a2*blo(wB);  z3 += a3*bhi(wB);
            }
            s_redE[(kq << 7) + j3] = (z0 + z1) + (z2 + z3);
        }
        __syncthreads();   // B3
        if (tid < 128)
            s_c[tid] = s_redE[tid] + s_redE[128+tid] + s_redE[256+tid] + s_redE[384+tid]
                     + s_pre[pb][256 + tid];
        __syncthreads();   // B4
        // ph5: MFMA + gates + vv; hh0: row-128 logit
        float vv[16];
        {
            float lgv[16], cvv[16];
            const float4* LG4 = (const float4*)s_LG;
            const float4* C4  = (const float4*)s_c;
            #pragma unroll
            for (int u = 0; u < 4; u++) {
                float4 lg = LG4[8*g + 2*u + h5];
                float4 cc = C4 [8*g + 2*u + h5];
                lgv[4*u+0]=lg.x; lgv[4*u+1]=lg.y; lgv[4*u+2]=lg.z; lgv[4*u+3]=lg.w;
                cvv[4*u+0]=cc.x; cvv[4*u+1]=cc.y; cvv[4*u+2]=cc.z; cvv[4*u+3]=cc.w;
            }
            #pragma unroll
            for (int i = 0; i < 2; i++) {
                const int cb = 2*hh + i;
                floatx16 a = (floatx16)(0.f);
                #pragma unroll
                for (int kb = 0; kb < 8; kb++) {
                    short8v bf = *(const short8v*)((const char*)s_frag +
                                   (((kb*4 + cb) << 10) + lane*16));
                    a = __builtin_amdgcn_mfma_f32_32x32x16_bf16(
                            __builtin_bit_cast(short8v, afru[kb]), bf, a, 0, 0, 0);
                }
                const int n = 32*cb + l31;
                const float qcv = qc[n], qnv = qn[n];
                #pragma unroll
                for (int r = 0; r < 16; r++) {
                    float gg = fsig(a[r] + cvv[r]);
                    float hn = qcv*lgv[r] + gg*hreg[i][r];
                    hreg[i][r] = hn;
                    float p = qnv*hn;
                    vv[r] = i ? (vv[r] + p) : p;
                }
            }
            if (hh == 0) {   // h row-128 logit via A-fragments (VALU)
                float part = 0.f;
                #pragma unroll
                for (int kb = 0; kb < 8; kb++) {
                    int kb0 = 16*kb + 8*h5;
                    uint4 u = afru[kb];
                    part += s_h128[kb0+0]*blo(u.x) + s_h128[kb0+1]*bhi(u.x);
                    part += s_h128[kb0+2]*blo(u.y) + s_h128[kb0+3]*bhi(u.y);
                    part += s_h128[kb0+4]*blo(u.z) + s_h128[kb0+5]*bhi(u.z);
                    part += s_h128[kb0+6]*blo(u.w) + s_h128[kb0+7]*bhi(u.w);
                }
                part += __shfl_xor(part, 32);
                if (h5 == 0) s_l128[32*g + l31] = part;
            }
        }
        __syncthreads();   // B5 (frag reads + s_h128 reads done; s_l128 ready)
        // ph6: frag rewrite + vv scatter + h row-128 update
        {
            #pragma unroll
            for (int i = 0; i < 2; i++) {
                const int cb = 2*hh + i;
                #pragma unroll
                for (int q = 0; q < 4; q++) {
                    int kb = 2*g + (q>>1);
                    int lanep = l31 + ((q&1) << 5);
                    int off = (((kb*4 + cb) << 10) + lanep*16 + (h5 << 3)) >> 2;
                    uint2 pr = make_uint2(pack2(hreg[i][4*q],   hreg[i][4*q+1]),
                                          pack2(hreg[i][4*q+2], hreg[i][4*q+3]));
                    *(uint2*)(s_frag + off) = pr;
                }
            }
            #pragma unroll
            for (int r = 0; r < 16; r++) {
                int d = 32*g + (r&3) + 8*(r>>2) + 4*h5;
                s_big[(hh*128 + d)*33 + l31] = vv[r];
            }
            if (tid < 128) {
                float gg = fsig(s_l128[tid] + s_c[tid]);
                s_h128[tid] = qc[128]*s_LG[tid] + gg*s_h128[tid];
            }
        }
        __syncthreads();   // B6
        // ph7: h_tilde reduce (t<128)
        if (tid < 128) {
            float a0 = 0.f, a1 = 0.f;
            #pragma unroll 8
            for (int j = 0; j < 32; j++) {
                a0 += s_big[tid*33 + j];
                a1 += s_big[(128 + tid)*33 + j];
            }
            s_htv[tid] = (a0 + a1 + qn[128]*s_h128[tid]) * frcp(s_scal[0]);
        }
        __syncthreads();   // B7
        // ph8: P6 = h_tilde . W5b (4-acc)
        {
            float4 fv = ((const float4*)s_htv)[(kq << 3) + (l31 & 7)];
            float z0 = 0.f, z1 = 0.f, z2 = 0.f, z3 = 0.f;
            #pragma unroll
            for (int s = 0; s < 8; s++) {
                float a0 = rlf(fv.x, s), a1 = rlf(fv.y, s);
                float a2 = rlf(fv.z, s), a3 = rlf(fv.w, s);
                unsigned wA = w5b[2*s], wB = w5b[2*s+1];
                z0 += a0*blo(wA);  z1 += a1*bhi(wA);
                z2 += a2*blo(wB);  z3 += a3*bhi(wB);
            }
            s_redE[(kq << 7) + j3] = (z0 + z1) + (z2 + z3);
        }
        __syncthreads();   // B8
        // ph9: y
        if (tid < 64) {
            float va = s_redE[lane]    + s_redE[128+lane] + s_redE[256+lane] + s_redE[384+lane]
                     + s_pre[pb][384 + lane];
            float vb = s_redE[64+lane] + s_redE[192+lane] + s_redE[320+lane] + s_redE[448+lane]
                     + s_pre[pb][448 + lane];
            float v = fsig(va) + fsig(vb);
            #pragma unroll
            for (int m = 32; m > 0; m >>= 1) v += __shfl_xor(v, m);
            if (lane == 0) out[b*SS + t + 1] = v * (1.0f / 128.0f);
        }
        // no trailing barrier: ph9 reads s_redE/s_pre[pb]; next ph1 writes
        // s_red/s_pre[1-pb]/s_q[pb] (qc dead after B6) — disjoint.
    }
}

extern "C" void kernel_launch(void* const* d_in, const int* in_sizes, int n_in,
                              void* d_out, int out_size, void* d_ws, size_t ws_size,
                              hipStream_t stream) {
    const int*   e_data  = (const int*)d_in[0];
    const int*   a_data  = (const int*)d_in[1];
    const int*   it_data = (const int*)d_in[2];
    const int*   at_data = (const int*)d_in[3];
    const float* qm  = (const float*)d_in[4];
    const float* h0  = (const float*)d_in[5];
    const float* Ee  = (const float*)d_in[6];
    const float* Eat = (const float*)d_in[7];
    const float* Eit = (const float*)d_in[8];
    const float* W1  = (const float*)d_in[9];
    const float* b1  = (const float*)d_in[10];
    const float* W2  = (const float*)d_in[11];
    const float* b2  = (const float*)d_in[12];
    const float* W3  = (const float*)d_in[13];
    const float* b3  = (const float*)d_in[14];
    const float* W4  = (const float*)d_in[15];
    const float* b4  = (const float*)d_in[16];
    const float* W5  = (const float*)d_in[17];
    const float* b5  = (const float*)d_in[18];
    float* out = (float*)d_out;
    unsigned* ws = (unsigned*)d_ws;

    k0_prep<<<dim3((123008 + 255) / 256), dim3(256), 0, stream>>>(W1, W2, W3, W4, W5, ws);
    k1_al<<<dim3(BB, 7), dim3(128), 0, stream>>>(e_data, a_data, at_data, Ee, Eat, b1, ws);
    k2_pre<<<dim3(BB, 7), dim3(512), 0, stream>>>(e_data, it_data, Eit, Ee, b2, b3, b4, b5, ws);
    lpkt_kernel<<<dim3(BB), dim3(NTH), 0, stream>>>(e_data, qm, h0, out, ws);
}